// Round 6
// baseline (165.160 us; speedup 1.0000x reference)
//
#include <hip/hip_runtime.h>
#include <math.h>

#define S_ 6
#define N_ 10000
#define C_ 128
#define D_ 4
#define H_ 4
#define P_ 8
#define HF_ 28
#define WF_ 50
#define M_ (HF_ * WF_)   // 1400
#define DH_ 32
#define SM_ (S_ * M_)    // 8400
// one fp8 value-copy: S*H*M pixels x 32 B = 1,075,200 B
#define ABYTES (S_ * H_ * M_ * 32)
#define VB_SH (M_ * 32)          // 44,800 B per (s,h) plane
#define CQ 64                    // queries per attn6 block
#define NCH ((N_ + CQ - 1) / CQ) // 157

#define NB_V ((SM_ + 31) / 32)   // 263 vproj blocks
#define NB_O ((N_ + 31) / 32)    // 313 OFFL blocks

typedef float floatx2 __attribute__((ext_vector_type(2)));

// ---------------------------------------------------------------------------
// Shared GEMM body, K=128, MRx4 micro-tile, k-blocked by 4 with ds_read_b128.
//   MODE 0 (vproj): out = A@B0 + bias0 -> fp8 e4m3 (single copy).
//   MODE 1 (OFFL):  out = (A+A2)@[B0|B1] + [bias0|bias1] -> fp32 (Mrows,96).
// ---------------------------------------------------------------------------
template <int NC, int MT, int MR, int MODE>
__device__ __forceinline__ void gemm_body(
    const float* __restrict__ A, const float* __restrict__ A2,
    const float* __restrict__ B0, const float* __restrict__ B1,
    const float* __restrict__ bias0, const float* __restrict__ bias1,
    float* __restrict__ outf, char* __restrict__ out8,
    int Mrows, int m0, int tid, int nthreads, float (*Alds)[132]) {
  constexpr int NTHR = (NC / 4) * (MT / MR);

  for (int i = tid; i < MT * 32; i += nthreads) {
    int r = i >> 5, k = (i & 31) * 4;
    int row = m0 + r;
    float4 v = make_float4(0.f, 0.f, 0.f, 0.f);
    if (row < Mrows) {
      v = *(const float4*)(A + (size_t)row * C_ + k);
      if (MODE == 1) {
        float4 v2 = *(const float4*)(A2 + (size_t)row * C_ + k);
        v.x += v2.x; v.y += v2.y; v.z += v2.z; v.w += v2.w;
      }
    }
    *(float4*)(&Alds[r][k]) = v;
  }
  __syncthreads();
  if (tid >= NTHR) return;

  int ci = tid % (NC / 4);
  int mi = tid / (NC / 4);
  int c0 = ci * 4, r0 = mi * MR;

  const float* bs;
  if (MODE == 1) bs = (c0 < 64) ? bias0 + c0 : bias1 + (c0 - 64);
  else bs = bias0 + c0;

  float acc[MR][4];
#pragma unroll
  for (int j = 0; j < MR; ++j)
#pragma unroll
    for (int cc = 0; cc < 4; ++cc) acc[j][cc] = bs[cc];

#pragma unroll 2
  for (int k4 = 0; k4 < C_; k4 += 4) {
    float bf[16];
#pragma unroll
    for (int kk = 0; kk < 4; ++kk) {
      int k = k4 + kk;
      float4 b4;
      if (MODE == 1)
        b4 = (c0 < 64) ? *(const float4*)(B0 + (size_t)k * 64 + c0)
                       : *(const float4*)(B1 + (size_t)k * 32 + (c0 - 64));
      else
        b4 = *(const float4*)(B0 + (size_t)k * NC + c0);
      bf[kk * 4 + 0] = b4.x; bf[kk * 4 + 1] = b4.y;
      bf[kk * 4 + 2] = b4.z; bf[kk * 4 + 3] = b4.w;
    }
    float af[MR * 4];
#pragma unroll
    for (int j = 0; j < MR; ++j) {
      float4 a4 = *(const float4*)(&Alds[r0 + j][k4]);
      af[j * 4 + 0] = a4.x; af[j * 4 + 1] = a4.y;
      af[j * 4 + 2] = a4.z; af[j * 4 + 3] = a4.w;
    }
#pragma unroll
    for (int j = 0; j < MR; ++j)
#pragma unroll
      for (int kk = 0; kk < 4; ++kk)
#pragma unroll
        for (int cc = 0; cc < 4; ++cc)
          acc[j][cc] = fmaf(af[j * 4 + kk], bf[kk * 4 + cc], acc[j][cc]);
  }

#pragma unroll
  for (int j = 0; j < MR; ++j) {
    int row = m0 + r0 + j;
    if (row >= Mrows) continue;
    if (MODE == 0) {
      int mm = row % M_;
      int h = c0 >> 5, d0 = c0 & 31;
      int s = row / M_;
      int w = __builtin_amdgcn_cvt_pk_fp8_f32(acc[j][0], acc[j][1], 0, false);
      w = __builtin_amdgcn_cvt_pk_fp8_f32(acc[j][2], acc[j][3], w, true);
      size_t hm = (size_t)s * H_ + h;
      *(int*)(out8 + (hm * M_ + mm) * 32 + d0) = w;
    } else if (MODE == 1) {
      *(float4*)(outf + (size_t)row * 96 + c0) =
          make_float4(acc[j][0], acc[j][1], acc[j][2], acc[j][3]);
    }
  }
}

// ---------------------------------------------------------------------------
__global__ __launch_bounds__(256) void prep_kernel(
    const float* __restrict__ value, const float* __restrict__ w_val,
    const float* __restrict__ b_val, char* __restrict__ vh8,
    const float* __restrict__ query, const float* __restrict__ query_pos,
    const float* __restrict__ w_off, const float* __restrict__ b_off,
    const float* __restrict__ w_attn, const float* __restrict__ b_attn,
    float* __restrict__ OFFL) {
  __shared__ float Alds[32][132];
  int bid = blockIdx.x;
  if (bid < NB_V) {
    gemm_body<128, 32, 4, 0>(value, nullptr, w_val, nullptr, b_val, nullptr,
                             nullptr, vh8, SM_, bid * 32, threadIdx.x, 256,
                             Alds);
  } else {
    gemm_body<96, 32, 4, 1>(query, query_pos, w_off, w_attn, b_off, b_attn,
                            OFFL, nullptr, N_, (bid - NB_V) * 32, threadIdx.x,
                            256, Alds);
  }
}

// ---------------------------------------------------------------------------
// attn6: block = (chalf, h, 64 queries); 256 thr. Double-buffered V half-
// plane (2 x 22.4 KB) + double-buffered param table (2 x 9.2 KB) -> ONE
// barrier per s: {stage(s+1) || params(s+1)} overlap gather(s); the stage's
// L2 latency hides under the long G phase instead of the short P phase.
// Lanes in G: 16 queries x 4 roles (rowsel,xsel), 16 channels each.
// ---------------------------------------------------------------------------
__global__ __launch_bounds__(256, 2) void attn6_kernel(
    const float* __restrict__ OFFL,     // (N,96): [0:64)=off, [64:96)=logits
    const float* __restrict__ refpts,   // (S,1,N,D,2)
    const int*   __restrict__ bev_mask, // (S,1,N,D)
    const char*  __restrict__ wsbase,   // value fp8 at +64, (sh,M,32B)
    float* __restrict__ slot) {         // (N,128) fp32, already /cnt
  __shared__ int4 Vbuf[2][M_];          // 44,800 B
  __shared__ int4 Pp[2][CQ * 9];        // 18,432 B  (total 63,232 B)

  int bid = blockIdx.x;
  int chalf = bid & 1;
  int h = (bid >> 1) & 3;
  int q0 = (bid >> 3) * CQ;
  int tid = threadIdx.x;

  // ---- G identity: wave = 16 q x 4 roles ---------------------------------
  int w = tid >> 6, lane = tid & 63;
  int role = lane & 3, ql16 = lane >> 2;
  int rowsel = role >> 1, xsel = role & 1;
  int xsh = xsel << 4;
  int qlG = w * 16 + ql16;
  int qG = q0 + qlG;
  bool qGv = (qG < N_);
  int qGc = qGv ? qG : (N_ - 1);

  // ---- P identity: thread covers samples (qA,pA) and (qA+32,pA) ----------
  int pA = tid & 7, qA = tid >> 3;
  int gqA = min(q0 + qA, N_ - 1);
  int gqB = min(q0 + qA + 32, N_ - 1);

  // ---- hoisted s-invariant params (softmax weight + offsets), 2 samples --
  float awA, oxA, oyA, awB, oxB, oyB;
  {
    const float* lg = OFFL + (size_t)gqA * 96 + 64 + h * 8;
    float e[8];
    float mx = -1e30f;
#pragma unroll
    for (int p = 0; p < 8; ++p) { e[p] = lg[p]; mx = fmaxf(mx, e[p]); }
    float sum = 0.f;
#pragma unroll
    for (int p = 0; p < 8; ++p) { e[p] = expf(e[p] - mx); sum += e[p]; }
    awA = e[pA] / sum;
    int pd = pA >> 2, dd = pA & 3;
    const float* ob = OFFL + (size_t)gqA * 96 + h * 16 + pd * 8 + dd * 2;
    oxA = ob[0]; oyA = ob[1];
  }
  {
    const float* lg = OFFL + (size_t)gqB * 96 + 64 + h * 8;
    float e[8];
    float mx = -1e30f;
#pragma unroll
    for (int p = 0; p < 8; ++p) { e[p] = lg[p]; mx = fmaxf(mx, e[p]); }
    float sum = 0.f;
#pragma unroll
    for (int p = 0; p < 8; ++p) { e[p] = expf(e[p] - mx); sum += e[p]; }
    awB = e[pA] / sum;
    int pd = pA >> 2, dd = pA & 3;
    const float* ob = OFFL + (size_t)gqB * 96 + h * 16 + pd * 8 + dd * 2;
    oxB = ob[0]; oyB = ob[1];
  }

  // ---- helpers ------------------------------------------------------------
  auto stage = [&](int s) {
    int b = s & 1;
    const char* gsrc = wsbase + 64 + (size_t)(s * H_ + h) * VB_SH + chalf * 16;
#pragma unroll
    for (int r = 0; r < 6; ++r) {
      int i = r * 256 + tid;
      if (i < M_) {
        __builtin_amdgcn_global_load_lds(
            (const __attribute__((address_space(1))) unsigned int*)(gsrc +
                                                                    (size_t)i *
                                                                        32),
            (__attribute__((address_space(3))) unsigned int*)&Vbuf[b][i], 16,
            0, 0);
      }
    }
  };

  auto psample = [&](int s, int b, int gq, int qloc, int p, float aw, float ox,
                     float oy) {
    int dd = p & 3;
    const float* rf = refpts + ((size_t)s * N_ + gq) * 8 + dd * 2;
    float rx = rf[0], ry = rf[1];
    const int* bm = bev_mask + ((size_t)s * N_ + gq) * D_;
    int4 bmv = *(const int4*)bm;
    float A = ((bmv.x | bmv.y | bmv.z | bmv.w) ? 1.f : 0.f) * aw;
    float ix = rx * (float)WF_ + ox - 0.5f;
    float iy = ry * (float)HF_ + oy - 0.5f;
    float xf = floorf(ix), yf = floorf(iy);
    int x0 = (int)xf, y0 = (int)yf;
    float fx = ix - xf, fy = iy - yf;
    float gx = 1.f - fx, gy = 1.f - fy;
    bool vx0 = (x0 >= 0) && (x0 < WF_);
    bool vx1 = (x0 >= -1) && (x0 < WF_ - 1);
    bool vy0 = (y0 >= 0) && (y0 < HF_);
    bool vy1 = (y0 >= -1) && (y0 < HF_ - 1);
    float w00 = (vx0 && vy0) ? gx * gy * A : 0.f;
    float w10 = (vx1 && vy0) ? fx * gy * A : 0.f;
    float w01 = (vx0 && vy1) ? gx * fy * A : 0.f;
    float w11 = (vx1 && vy1) ? fx * fy * A : 0.f;
    int yt = min(max(y0, 0), HF_ - 1) * WF_;
    int yb = min(max(y0 + 1, 0), HF_ - 1) * WF_;
    int xc0 = min(max(x0, 0), WF_ - 1);
    int xc1 = min(max(x0 + 1, 0), WF_ - 1);
    int4 pk;
    pk.x = (yt + xc0) | ((yt + xc1) << 16);
    pk.y = (yb + xc0) | ((yb + xc1) << 16);
    union { _Float16 hf[2]; int iv; } u01, u23;
    u01.hf[0] = (_Float16)w00; u01.hf[1] = (_Float16)w10;
    u23.hf[0] = (_Float16)w01; u23.hf[1] = (_Float16)w11;
    pk.z = u01.iv;
    pk.w = u23.iv;
    Pp[b][qloc * 9 + p] = pk;
  };

  floatx2 acc[8] = {{0.f, 0.f}, {0.f, 0.f}, {0.f, 0.f}, {0.f, 0.f},
                    {0.f, 0.f}, {0.f, 0.f}, {0.f, 0.f}, {0.f, 0.f}};

  // ---- prologue: plane 0 in flight, params 0 ready -----------------------
  stage(0);
  psample(0, 0, gqA, qA, pA, awA, oxA, oyA);
  psample(0, 0, gqB, qA + 32, pA, awB, oxB, oyB);
  __syncthreads();  // drains stage(0) vmcnt; Pp[0] visible

  // ---- main loop: ONE barrier per s --------------------------------------
  for (int s = 0; s < S_; ++s) {
    if (s + 1 < S_) {
      stage(s + 1);  // -> Vbuf[(s+1)&1], drained by end-of-iter barrier
      psample(s + 1, (s + 1) & 1, gqA, qA, pA, awA, oxA, oyA);
      psample(s + 1, (s + 1) & 1, gqB, qA + 32, pA, awB, oxB, oyB);
    }
    // gather(s): reads Vbuf[s&1] + Pp[s&1]
    {
      int b = s & 1;
      const int4* pp = &Pp[b][qlG * 9];
      const int4* vb = Vbuf[b];
#pragma unroll
      for (int p = 0; p < 8; ++p) {
        int4 prm = pp[p];  // broadcast across the 4 role-lanes of a query
        int vword = rowsel ? prm.y : prm.x;
        int pix = (int)(((unsigned)vword >> xsh) & 0xffffu);
        int wword = rowsel ? prm.w : prm.z;
        union { unsigned short u; _Float16 hf; } cu;
        cu.u = (unsigned short)((unsigned)wword >> xsh);
        float wgt = (float)cu.hf;
        int4 tv = vb[pix];
        floatx2 wv = {wgt, wgt};
        acc[0] += __builtin_amdgcn_cvt_pk_f32_fp8(tv.x, false) * wv;
        acc[1] += __builtin_amdgcn_cvt_pk_f32_fp8(tv.x, true)  * wv;
        acc[2] += __builtin_amdgcn_cvt_pk_f32_fp8(tv.y, false) * wv;
        acc[3] += __builtin_amdgcn_cvt_pk_f32_fp8(tv.y, true)  * wv;
        acc[4] += __builtin_amdgcn_cvt_pk_f32_fp8(tv.z, false) * wv;
        acc[5] += __builtin_amdgcn_cvt_pk_f32_fp8(tv.z, true)  * wv;
        acc[6] += __builtin_amdgcn_cvt_pk_f32_fp8(tv.w, false) * wv;
        acc[7] += __builtin_amdgcn_cvt_pk_f32_fp8(tv.w, true)  * wv;
      }
    }
    __syncthreads();  // G(s) done everywhere; stage(s+1)/Pp[(s+1)&1] landed
  }

  // ---- fold roles (xsel bit0, rowsel bit1), /cnt, write slot -------------
  float av[16];
#pragma unroll
  for (int k = 0; k < 8; ++k) { av[2 * k] = acc[k][0]; av[2 * k + 1] = acc[k][1]; }
#pragma unroll
  for (int k = 0; k < 16; ++k) av[k] += __shfl_xor(av[k], 1);
#pragma unroll
  for (int k = 0; k < 16; ++k) av[k] += __shfl_xor(av[k], 2);

  if (role == 0 && qGv) {
    int cnt = 0;
#pragma unroll
    for (int s = 0; s < S_; ++s) {
      const int* bm = bev_mask + ((size_t)s * N_ + qGc) * D_;
      int4 bmv = *(const int4*)bm;
      cnt += (bmv.x | bmv.y | bmv.z | bmv.w) ? 1 : 0;
    }
    float inv = 1.f / (float)(cnt > 0 ? cnt : 1);
    float* dst = slot + (size_t)qG * C_ + h * DH_ + chalf * 16;
    *(float4*)(dst + 0)  = make_float4(av[0] * inv, av[1] * inv, av[2] * inv, av[3] * inv);
    *(float4*)(dst + 4)  = make_float4(av[4] * inv, av[5] * inv, av[6] * inv, av[7] * inv);
    *(float4*)(dst + 8)  = make_float4(av[8] * inv, av[9] * inv, av[10] * inv, av[11] * inv);
    *(float4*)(dst + 12) = make_float4(av[12] * inv, av[13] * inv, av[14] * inv, av[15] * inv);
  }
}

// ---------------------------------------------------------------------------
// outproj: out = slot@w_out + b_out + query. 32-query tile per block.
// ---------------------------------------------------------------------------
__global__ __launch_bounds__(256) void outproj_kernel(
    const float* __restrict__ slot, const float* __restrict__ query,
    const float* __restrict__ w_out, const float* __restrict__ b_out,
    float* __restrict__ out) {
  __shared__ float slds[32][132];
  int q0 = blockIdx.x * 32, tid = threadIdx.x;

  for (int i = tid; i < 32 * 32; i += 256) {
    int r = i >> 5, k = (i & 31) * 4;
    int qc = min(q0 + r, N_ - 1);
    *(float4*)(&slds[r][k]) = *(const float4*)(slot + (size_t)qc * C_ + k);
  }
  __syncthreads();

  {
    int ci = tid & 31, mi = tid >> 5;
    int c0 = ci * 4, r0 = mi * 4;
    float acc[4][4];
#pragma unroll
    for (int j = 0; j < 4; ++j) {
      int qq = min(q0 + r0 + j, N_ - 1);
      float4 qv = *(const float4*)(query + (size_t)qq * C_ + c0);
      float4 bv = *(const float4*)(b_out + c0);
      acc[j][0] = bv.x + qv.x; acc[j][1] = bv.y + qv.y;
      acc[j][2] = bv.z + qv.z; acc[j][3] = bv.w + qv.w;
    }
#pragma unroll 2
    for (int k4 = 0; k4 < C_; k4 += 4) {
      float bf[16];
#pragma unroll
      for (int kk = 0; kk < 4; ++kk) {
        float4 b4 = *(const float4*)(w_out + (size_t)(k4 + kk) * C_ + c0);
        bf[kk * 4 + 0] = b4.x; bf[kk * 4 + 1] = b4.y;
        bf[kk * 4 + 2] = b4.z; bf[kk * 4 + 3] = b4.w;
      }
      float af[16];
#pragma unroll
      for (int j = 0; j < 4; ++j) {
        float4 a4 = *(const float4*)(&slds[r0 + j][k4]);
        af[j * 4 + 0] = a4.x; af[j * 4 + 1] = a4.y;
        af[j * 4 + 2] = a4.z; af[j * 4 + 3] = a4.w;
      }
#pragma unroll
      for (int j = 0; j < 4; ++j)
#pragma unroll
        for (int kk = 0; kk < 4; ++kk)
#pragma unroll
          for (int cc = 0; cc < 4; ++cc)
            acc[j][cc] = fmaf(af[j * 4 + kk], bf[kk * 4 + cc], acc[j][cc]);
    }
#pragma unroll
    for (int j = 0; j < 4; ++j) {
      int qq = q0 + r0 + j;
      if (qq < N_)
        *(float4*)(out + (size_t)qq * C_ + c0) =
            make_float4(acc[j][0], acc[j][1], acc[j][2], acc[j][3]);
    }
  }
}

// ---------------------------------------------------------------------------
extern "C" void kernel_launch(void* const* d_in, const int* in_sizes, int n_in,
                              void* d_out, int out_size, void* d_ws, size_t ws_size,
                              hipStream_t stream) {
  const float* query     = (const float*)d_in[0];
  const float* value     = (const float*)d_in[2];
  const float* query_pos = (const float*)d_in[3];
  const float* refpts    = (const float*)d_in[4];
  const int*   bev_mask  = (const int*)d_in[5];
  const float* w_off     = (const float*)d_in[6];
  const float* b_off     = (const float*)d_in[7];
  const float* w_attn    = (const float*)d_in[8];
  const float* b_attn    = (const float*)d_in[9];
  const float* w_val     = (const float*)d_in[10];
  const float* b_val     = (const float*)d_in[11];
  const float* w_out     = (const float*)d_in[12];
  const float* b_out     = (const float*)d_in[13];

  char* ws = (char*)d_ws;
  char* vh8   = ws + 64;                                        // ABYTES
  float* OFFL = (float*)(ws + 64 + 2 * (size_t)ABYTES + 64);    // 3,840,000 B
  float* SLOT = (float*)(ws + 64 + 2 * (size_t)ABYTES + 64 +
                         (size_t)N_ * 96 * 4);                  // 5,120,000 B

  prep_kernel<<<NB_V + NB_O, 256, 0, stream>>>(
      value, w_val, b_val, vh8, query, query_pos, w_off, b_off, w_attn, b_attn,
      OFFL);
  attn6_kernel<<<NCH * H_ * 2, 256, 0, stream>>>(OFFL, refpts, bev_mask, ws,
                                                 SLOT);
  outproj_kernel<<<(N_ + 31) / 32, 256, 0, stream>>>(SLOT, query, w_out, b_out,
                                                     (float*)d_out);
}

// Round 7
// 143.182 us; speedup vs baseline: 1.1535x; 1.1535x over previous
//
#include <hip/hip_runtime.h>
#include <math.h>

#define S_ 6
#define N_ 10000
#define C_ 128
#define D_ 4
#define H_ 4
#define P_ 8
#define HF_ 28
#define WF_ 50
#define M_ (HF_ * WF_)   // 1400
#define DH_ 32
#define SM_ (S_ * M_)    // 8400
#define QB_ 4            // queries per attn block (256 threads, 64 lanes/query)
// one fp8 value-copy: S*H*M pixels x 32 B = 1,075,200 B
#define ABYTES (S_ * H_ * M_ * 32)

#define MT_ 64                     // GEMM rows per block (R7: 32 -> 64)
#define NB_V ((SM_ + MT_ - 1) / MT_)   // 132 vproj blocks
#define NB_O ((N_ + MT_ - 1) / MT_)    // 157 OFFL blocks

typedef float floatx2 __attribute__((ext_vector_type(2)));
typedef _Float16 half4h __attribute__((ext_vector_type(4)));

// ---------------------------------------------------------------------------
// Shared GEMM body, K=128, MRx4 micro-tile, k-blocked by 4 with ds_read_b128.
//   MODE 0 (vproj): out = A@B0 + bias0 -> fp8 e4m3, DUAL layout (A/B parity).
//   MODE 1 (OFFL):  out = (A+A2)@[B0|B1] + [bias0|bias1] -> fp32 (Mrows,96).
// MT=64/MR=8: halves B-traffic-from-L2 per output vs the 32/4 tile.
// ---------------------------------------------------------------------------
template <int NC, int MT, int MR, int MODE>
__device__ __forceinline__ void gemm_body(
    const float* __restrict__ A, const float* __restrict__ A2,
    const float* __restrict__ B0, const float* __restrict__ B1,
    const float* __restrict__ bias0, const float* __restrict__ bias1,
    float* __restrict__ outf, char* __restrict__ out8,
    int Mrows, int m0, int tid, int nthreads, float (*Alds)[132]) {
  constexpr int NTHR = (NC / 4) * (MT / MR);

  for (int i = tid; i < MT * 32; i += nthreads) {
    int r = i >> 5, k = (i & 31) * 4;
    int row = m0 + r;
    float4 v = make_float4(0.f, 0.f, 0.f, 0.f);
    if (row < Mrows) {
      v = *(const float4*)(A + (size_t)row * C_ + k);
      if (MODE == 1) {
        float4 v2 = *(const float4*)(A2 + (size_t)row * C_ + k);
        v.x += v2.x; v.y += v2.y; v.z += v2.z; v.w += v2.w;
      }
    }
    *(float4*)(&Alds[r][k]) = v;
  }
  __syncthreads();
  if (tid >= NTHR) return;

  int ci = tid % (NC / 4);
  int mi = tid / (NC / 4);
  int c0 = ci * 4, r0 = mi * MR;

  const float* bs;
  if (MODE == 1) bs = (c0 < 64) ? bias0 + c0 : bias1 + (c0 - 64);
  else bs = bias0 + c0;

  float acc[MR][4];
#pragma unroll
  for (int j = 0; j < MR; ++j)
#pragma unroll
    for (int cc = 0; cc < 4; ++cc) acc[j][cc] = bs[cc];

#pragma unroll 2
  for (int k4 = 0; k4 < C_; k4 += 4) {
    float bf[16];
#pragma unroll
    for (int kk = 0; kk < 4; ++kk) {
      int k = k4 + kk;
      float4 b4;
      if (MODE == 1)
        b4 = (c0 < 64) ? *(const float4*)(B0 + (size_t)k * 64 + c0)
                       : *(const float4*)(B1 + (size_t)k * 32 + (c0 - 64));
      else
        b4 = *(const float4*)(B0 + (size_t)k * NC + c0);
      bf[kk * 4 + 0] = b4.x; bf[kk * 4 + 1] = b4.y;
      bf[kk * 4 + 2] = b4.z; bf[kk * 4 + 3] = b4.w;
    }
#pragma unroll
    for (int j = 0; j < MR; ++j) {
      float4 a4 = *(const float4*)(&Alds[r0 + j][k4]);
      float af0 = a4.x, af1 = a4.y, af2 = a4.z, af3 = a4.w;
#pragma unroll
      for (int cc = 0; cc < 4; ++cc) {
        acc[j][cc] = fmaf(af0, bf[0 * 4 + cc], acc[j][cc]);
        acc[j][cc] = fmaf(af1, bf[1 * 4 + cc], acc[j][cc]);
        acc[j][cc] = fmaf(af2, bf[2 * 4 + cc], acc[j][cc]);
        acc[j][cc] = fmaf(af3, bf[3 * 4 + cc], acc[j][cc]);
      }
    }
  }

#pragma unroll
  for (int j = 0; j < MR; ++j) {
    int row = m0 + r0 + j;
    if (row >= Mrows) continue;
    if (MODE == 0) {
      int s = row / M_, mm = row % M_;
      int y = mm / WF_, x = mm % WF_;
      int h = c0 >> 5, d0 = c0 & 31;
      int w = __builtin_amdgcn_cvt_pk_fp8_f32(acc[j][0], acc[j][1], 0, false);
      w = __builtin_amdgcn_cvt_pk_fp8_f32(acc[j][2], acc[j][3], w, true);
      size_t hm = (size_t)s * H_ + h;
      *(int*)(out8 + (hm * M_ + mm) * 32 + d0) = w;       // copy A
      if (x > 0) {                                        // copy B
        int kp = (x - 1) >> 1, slot = 1 - (x & 1);
        *(int*)(out8 + ABYTES + ((hm * HF_ + y) * 25 + kp) * 64 +
                slot * 32 + d0) = w;
      }
    } else if (MODE == 1) {
      *(float4*)(outf + (size_t)row * 96 + c0) =
          make_float4(acc[j][0], acc[j][1], acc[j][2], acc[j][3]);
    }
  }
}

// ---------------------------------------------------------------------------
__global__ __launch_bounds__(256) void prep_kernel(
    const float* __restrict__ value, const float* __restrict__ w_val,
    const float* __restrict__ b_val, char* __restrict__ vh8,
    const float* __restrict__ query, const float* __restrict__ query_pos,
    const float* __restrict__ w_off, const float* __restrict__ b_off,
    const float* __restrict__ w_attn, const float* __restrict__ b_attn,
    float* __restrict__ OFFL) {
  __shared__ float Alds[MT_][132];
  int bid = blockIdx.x;
  if (bid < NB_V) {
    gemm_body<128, MT_, 8, 0>(value, nullptr, w_val, nullptr, b_val, nullptr,
                              nullptr, vh8, SM_, bid * MT_, threadIdx.x, 256,
                              Alds);
  } else {
    gemm_body<96, MT_, 8, 1>(query, query_pos, w_off, w_attn, b_off, b_attn,
                             OFFL, nullptr, N_, (bid - NB_V) * MT_,
                             threadIdx.x, 256, Alds);
  }
}

// ---------------------------------------------------------------------------
// Fused deformable sampling + output projection. QB_=4 queries / 256 threads:
// 64 lanes per query, samples split across the two 32-lane halves (ssel).
// launch_bounds(256,3): cap occupancy at 3 waves/SIMD so the register
// allocator keeps the batched gather loads (8 dwordx4 in flight per batch)
// in VGPRs instead of serializing them (R1: VGPR=32 killed MLP, dur flat).
// ---------------------------------------------------------------------------
__global__ __launch_bounds__(256, 3) void attn2_kernel(
    const float* __restrict__ OFFL,     // (N,96): [0:64)=off, [64:96)=logits
    const float* __restrict__ refpts,   // (S,1,N,D,2)
    const int*   __restrict__ bev_mask, // (S,1,N,D)
    const char*  __restrict__ wsbase,   // d_ws base; value data at +64 (dual)
    const float* __restrict__ query,    // (N,128)
    const float* __restrict__ w_out,    // (128,128)
    const float* __restrict__ b_out,    // (128)
    float* __restrict__ out) {          // (N,128)
  int n0 = blockIdx.x * QB_;
  int tid = threadIdx.x;

  __shared__ int2   sidx[QB_ * 194];    // 6208 B
  __shared__ half4h swh[QB_ * 194];     // 6208 B
  __shared__ float  offp[QB_ * 64];     // 1024 B
  __shared__ float  logtp[QB_ * 32];    //  512 B
  __shared__ float  awp[QB_ * 32];      //  512 B
  __shared__ float  reflp[QB_ * 48];    //  768 B
  __shared__ int    smaskp[QB_ * 6];    //   96 B
  __shared__ float  slp[QB_ * 132];     // 2112 B   (total ~17.4 KB)

  // ---- stage -------------------------------------------------------------
  for (int i = tid; i < QB_ * 96; i += 256) {
    int q = i / 96, c = i % 96;
    float v = OFFL[(size_t)(n0 + q) * 96 + c];
    if (c < 64) offp[q * 64 + c] = v; else logtp[q * 32 + c - 64] = v;
  }
  for (int i = tid; i < QB_ * 48; i += 256) {
    int q = i / 48, rem = i % 48;
    int s = rem >> 3, r8 = rem & 7;
    reflp[q * 48 + rem] = refpts[((size_t)s * N_ + (n0 + q)) * 8 + r8];
  }
  if (tid < QB_ * 6) {
    int q = tid / 6, s = tid % 6;
    const int* bm = bev_mask + ((size_t)s * N_ + (n0 + q)) * D_;
    smaskp[tid] = (bm[0] | bm[1] | bm[2] | bm[3]) ? 1 : 0;
  }
  __syncthreads();

  // ---- softmax over P per head -------------------------------------------
  if (tid < QB_ * 32) {
    int q = tid >> 5, j = tid & 31, h = j >> 3;
    float mx = -1e30f;
#pragma unroll
    for (int p = 0; p < P_; ++p) mx = fmaxf(mx, logtp[q * 32 + h * P_ + p]);
    float sum = 0.f;
#pragma unroll
    for (int p = 0; p < P_; ++p) sum += expf(logtp[q * 32 + h * P_ + p] - mx);
    awp[q * 32 + j] = expf(logtp[q * 32 + j] - mx) / sum;
  }
  __syncthreads();

  // ---- per-sample params: j = s*32 + p*4 + h; smask folded into weights --
  for (int i = tid; i < QB_ * 192; i += 256) {
    int q = i / 192, j = i % 192;
    int s = j >> 5, w32 = j & 31, p = w32 >> 2, h = w32 & 3;
    int pd = p >> 2, dd = p & 3;
    float rx = reflp[q * 48 + s * 8 + dd * 2 + 0];
    float ry = reflp[q * 48 + s * 8 + dd * 2 + 1];
    float ox = offp[q * 64 + h * 16 + pd * 8 + dd * 2 + 0];
    float oy = offp[q * 64 + h * 16 + pd * 8 + dd * 2 + 1];
    float ix = rx * (float)WF_ + ox - 0.5f;
    float iy = ry * (float)HF_ + oy - 0.5f;
    float x0f = floorf(ix), y0f = floorf(iy);
    int x0 = (int)x0f, y0 = (int)y0f;
    float wx1 = ix - x0f, wy1 = iy - y0f;
    float wx0 = 1.f - wx1, wy0 = 1.f - wy1;
    float a = awp[q * 32 + h * P_ + p] * (float)smaskp[q * 6 + s];
    bool vx0 = (x0 >= 0) && (x0 < WF_);
    bool vx1 = (x0 + 1 >= 0) && (x0 + 1 < WF_);
    bool vy0 = (y0 >= 0) && (y0 < HF_);
    bool vy1 = (y0 + 1 >= 0) && (y0 + 1 < HF_);
    int y0c = min(max(y0, 0), HF_ - 1);
    int y1c = min(max(y0 + 1, 0), HF_ - 1);
    int hm = s * H_ + h;
    int itop, ibot;
    if (x0 >= 0 && x0 <= WF_ - 2 && !(x0 & 1)) {
      itop = (hm * M_ + y0c * WF_ + x0) * 32;        // copy A, aligned
      ibot = (hm * M_ + y1c * WF_ + x0) * 32;
    } else if (x0 >= 1 && x0 <= WF_ - 1 && (x0 & 1)) {
      int kp = (x0 - 1) >> 1;                        // copy B, aligned
      itop = ABYTES + ((hm * HF_ + y0c) * 25 + kp) * 64;
      ibot = ABYTES + ((hm * HF_ + y1c) * 25 + kp) * 64;
    } else if (x0 == -1) {
      itop = (hm * M_ + y0c * WF_) * 32 - 32;        // guard-backed
      ibot = (hm * M_ + y1c * WF_) * 32 - 32;
    } else {
      itop = ibot = 0;  // all weights 0
    }
    float w00 = (vx0 && vy0) ? wx0 * wy0 * a : 0.f;
    float w10 = (vx1 && vy0) ? wx1 * wy0 * a : 0.f;
    float w01 = (vx0 && vy1) ? wx0 * wy1 * a : 0.f;
    float w11 = (vx1 && vy1) ? wx1 * wy1 * a : 0.f;
    sidx[q * 194 + j] = make_int2(itop + 64, ibot + 64);
    // role order: [w00(x0,top), w10(x1,top), w01(x0,bot), w11(x1,bot)]
    half4h wv = {(_Float16)w00, (_Float16)w10, (_Float16)w01, (_Float16)w11};
    swh[q * 194 + j] = wv;
  }
  __syncthreads();

  // ---- gather: 64 lanes/query; 3 batches of 8 dwordx4 in flight ----------
  {
    int q = tid >> 6, lane = tid & 63;
    int ssel = lane >> 5;             // which 24-sample half (s=0..2 / 3..5)
    int t = lane & 31, h = t >> 3, c8 = t & 7;
    int rowsel = (c8 >> 2) & 1;       // 0=top row, 1=bottom row
    int xsel   = (c8 >> 1) & 1;       // 0=x0, 1=x1
    int chalf  = c8 & 1;              // which 16 channels
    int role   = c8 >> 1;             // weight index (w00,w10,w01,w11)
    int lanebyte = xsel * 32 + chalf * 16;
    const int* sxi = (const int*)(sidx + q * 194);          // [j*2+rowsel]
    const _Float16* swq = (const _Float16*)(swh + q * 194); // [j*4+role]

    floatx2 acc[8] = {{0.f, 0.f}, {0.f, 0.f}, {0.f, 0.f}, {0.f, 0.f},
                      {0.f, 0.f}, {0.f, 0.f}, {0.f, 0.f}, {0.f, 0.f}};

    // 3 batches of 8: issue all 8 scattered dwordx4 of a batch back-to-back
    // before any consumption -> >=8 outstanding L2 requests per wave.
#pragma unroll
    for (int b = 0; b < 3; ++b) {
      int offR[8];
      _Float16 wRb[8];
#pragma unroll
      for (int u = 0; u < 8; ++u) {
        int j = (ssel * 3 + b) * 32 + u * 4 + h;
        offR[u] = sxi[j * 2 + rowsel];
        wRb[u] = swq[j * 4 + role];
      }
      int4 tq[8];
#pragma unroll
      for (int u = 0; u < 8; ++u)
        tq[u] = *(const int4*)(wsbase + (offR[u] + lanebyte));
#pragma unroll
      for (int u = 0; u < 8; ++u) {
        float w = (float)wRb[u];
        floatx2 wv = {w, w};
        acc[0] += __builtin_amdgcn_cvt_pk_f32_fp8(tq[u].x, false) * wv;
        acc[1] += __builtin_amdgcn_cvt_pk_f32_fp8(tq[u].x, true)  * wv;
        acc[2] += __builtin_amdgcn_cvt_pk_f32_fp8(tq[u].y, false) * wv;
        acc[3] += __builtin_amdgcn_cvt_pk_f32_fp8(tq[u].y, true)  * wv;
        acc[4] += __builtin_amdgcn_cvt_pk_f32_fp8(tq[u].z, false) * wv;
        acc[5] += __builtin_amdgcn_cvt_pk_f32_fp8(tq[u].z, true)  * wv;
        acc[6] += __builtin_amdgcn_cvt_pk_f32_fp8(tq[u].w, false) * wv;
        acc[7] += __builtin_amdgcn_cvt_pk_f32_fp8(tq[u].w, true)  * wv;
      }
    }
    float av[16];
#pragma unroll
    for (int k = 0; k < 8; ++k) { av[2 * k] = acc[k][0]; av[2 * k + 1] = acc[k][1]; }
    // fold x-halves (bit1), rows (bit2), then sample-halves (bit5)
#pragma unroll
    for (int k = 0; k < 16; ++k) av[k] += __shfl_xor(av[k], 2);
#pragma unroll
    for (int k = 0; k < 16; ++k) av[k] += __shfl_xor(av[k], 4);
#pragma unroll
    for (int k = 0; k < 16; ++k) av[k] += __shfl_xor(av[k], 32);

    int cnt = smaskp[q * 6 + 0] + smaskp[q * 6 + 1] + smaskp[q * 6 + 2] +
              smaskp[q * 6 + 3] + smaskp[q * 6 + 4] + smaskp[q * 6 + 5];
    float inv = 1.f / (float)(cnt > 0 ? cnt : 1);
    if (ssel == 0 && c8 < 2) {  // lanes hold the folded 16-ch halves of head h
      float* dst = &slp[q * 132 + h * DH_ + chalf * 16];
#pragma unroll
      for (int k = 0; k < 16; ++k) dst[k] = av[k] * inv;
    }
  }
  __syncthreads();

  // ---- tiled output projection: out = sl@w_out + b_out + query -----------
  // 64 lanes/query: k-loop split across the two 32-lane halves, folded.
  {
    int q2 = tid >> 6, lane = tid & 63;
    int khalf = lane >> 5;
    int c0 = (lane & 31) * 4;
    int n = n0 + q2;
    floatx2 r01 = {0.f, 0.f};
    floatx2 r23 = {0.f, 0.f};
    int k0 = khalf * 64;
#pragma unroll 4
    for (int kk = 0; kk < 64; ++kk) {
      int k = k0 + kk;
      floatx2 a = {slp[q2 * 132 + k], slp[q2 * 132 + k]};
      float4 w4 = *(const float4*)(w_out + (size_t)k * C_ + c0);
      floatx2 w01 = {w4.x, w4.y}, w23 = {w4.z, w4.w};
      r01 += a * w01;
      r23 += a * w23;
    }
    r01[0] += __shfl_xor(r01[0], 32);
    r01[1] += __shfl_xor(r01[1], 32);
    r23[0] += __shfl_xor(r23[0], 32);
    r23[1] += __shfl_xor(r23[1], 32);
    if (lane < 32) {
      float4 qv = *(const float4*)(query + (size_t)n * C_ + c0);
      float4 bv = *(const float4*)(b_out + c0);
      *(float4*)(out + (size_t)n * C_ + c0) =
          make_float4(r01[0] + bv.x + qv.x, r01[1] + bv.y + qv.y,
                      r23[0] + bv.z + qv.z, r23[1] + bv.w + qv.w);
    }
  }
}

// ---------------------------------------------------------------------------
extern "C" void kernel_launch(void* const* d_in, const int* in_sizes, int n_in,
                              void* d_out, int out_size, void* d_ws, size_t ws_size,
                              hipStream_t stream) {
  const float* query     = (const float*)d_in[0];
  const float* value     = (const float*)d_in[2];
  const float* query_pos = (const float*)d_in[3];
  const float* refpts    = (const float*)d_in[4];
  const int*   bev_mask  = (const int*)d_in[5];
  const float* w_off     = (const float*)d_in[6];
  const float* b_off     = (const float*)d_in[7];
  const float* w_attn    = (const float*)d_in[8];
  const float* b_attn    = (const float*)d_in[9];
  const float* w_val     = (const float*)d_in[10];
  const float* b_val     = (const float*)d_in[11];
  const float* w_out     = (const float*)d_in[12];
  const float* b_out     = (const float*)d_in[13];

  char* ws = (char*)d_ws;
  char* vh8   = ws + 64;                   // dual copies: 2*ABYTES = 2,150,400
  float* OFFL = (float*)(ws + 64 + 2 * (size_t)ABYTES + 64);   // 3,840,000 B

  prep_kernel<<<NB_V + NB_O, 256, 0, stream>>>(
      value, w_val, b_val, vh8, query, query_pos, w_off, b_off, w_attn, b_attn,
      OFFL);
  attn2_kernel<<<N_ / QB_, 256, 0, stream>>>(OFFL, refpts, bev_mask, ws,
                                             query, w_out, b_out,
                                             (float*)d_out);
}